// Round 1
// baseline (762.136 us; speedup 1.0000x reference)
//
#include <hip/hip_runtime.h>

// ---------------------------------------------------------------------------
// AugmentedMemoryScaledDotProductAttention on MI355X (gfx950)
// B=8 H=8 NQ=NK=1024 D_MODEL=1024 DK=DV=128 M=16  (NKM=1040, padded to 1056)
//
// Pipeline:
//  1. split f32 -> (bf16 hi, bf16 lo) for queries/keys; plain bf16 for values
//  2. transpose+split weights Wq/Wk; transpose+cvt Wv/Wo
//  3. split-bf16 (3xMFMA) GEMM: Q-proj, K-proj ; plain bf16 GEMM: V-proj
//  4. attention: S = scale*(Qh.Kh + Qh.Kl + Ql.Kh); e = mask? 0 : exp(s)
//     (no max subtraction -- logits bounded);  l = sum e ;  O = (e @ V)/l ;
//     unnormalized e written to att region of d_out
//  5. rescale kernel: att *= 1/l   (att now = softmax probabilities)
//  6. plain bf16 GEMM: out = O @ Wo + bo  -> f32 d_out
// ---------------------------------------------------------------------------

typedef unsigned short u16;
typedef __bf16  bf16x8 __attribute__((ext_vector_type(8)));
typedef short   s16x8  __attribute__((ext_vector_type(8)));
typedef float   f32x4  __attribute__((ext_vector_type(4)));

#define MFMA_BF16(a, b, c) __builtin_amdgcn_mfma_f32_16x16x32_bf16((a), (b), (c), 0, 0, 0)

#define NB     8
#define NH     8
#define NQS    1024
#define NKS    1024
#define NKM    1040      // NK + M
#define KSP    1056      // padded key stride (NKM rounded to 32)
#define DKV    128
#define DMODEL 1024
#define SCALE_QK 0.088388347648318447f   // 1/sqrt(128)

__device__ __forceinline__ u16 f2bf(float f) {
  unsigned u = __builtin_bit_cast(unsigned, f);
  u += 0x7fffu + ((u >> 16) & 1u);
  return (u16)(u >> 16);
}
__device__ __forceinline__ float bf2f(u16 h) {
  unsigned u = ((unsigned)h) << 16;
  return __builtin_bit_cast(float, u);
}
__device__ __forceinline__ bf16x8 ld_bf8(const u16* p) {
  s16x8 r = *(const s16x8*)p;
  return __builtin_bit_cast(bf16x8, r);
}

// ---------------------------------------------------------------- elementwise
__global__ void split_kernel(const float* __restrict__ in,
                             u16* __restrict__ hi, u16* __restrict__ lo, int n4) {
  for (int i = blockIdx.x * blockDim.x + threadIdx.x; i < n4;
       i += gridDim.x * blockDim.x) {
    float4 v = ((const float4*)in)[i];
    ushort4 h, l;
    h.x = f2bf(v.x); l.x = f2bf(v.x - bf2f(h.x));
    h.y = f2bf(v.y); l.y = f2bf(v.y - bf2f(h.y));
    h.z = f2bf(v.z); l.z = f2bf(v.z - bf2f(h.z));
    h.w = f2bf(v.w); l.w = f2bf(v.w - bf2f(h.w));
    ((ushort4*)hi)[i] = h;
    ((ushort4*)lo)[i] = l;
  }
}

__global__ void cvt_kernel(const float* __restrict__ in, u16* __restrict__ out, int n4) {
  for (int i = blockIdx.x * blockDim.x + threadIdx.x; i < n4;
       i += gridDim.x * blockDim.x) {
    float4 v = ((const float4*)in)[i];
    ushort4 h;
    h.x = f2bf(v.x); h.y = f2bf(v.y); h.z = f2bf(v.z); h.w = f2bf(v.w);
    ((ushort4*)out)[i] = h;
  }
}

// W is (in=1024, out=1024) row-major; write Wt (out, in) row-major.
__global__ void wtrans_split_kernel(const float* __restrict__ w,
                                    u16* __restrict__ th, u16* __restrict__ tl) {
  int idx = blockIdx.x * 256 + threadIdx.x;   // 1M threads
  int i = idx >> 10, o = idx & 1023;
  float v = w[idx];
  u16 hh = f2bf(v);
  th[o * 1024 + i] = hh;
  tl[o * 1024 + i] = f2bf(v - bf2f(hh));
}

__global__ void wtrans_cvt_kernel(const float* __restrict__ w, u16* __restrict__ t) {
  int idx = blockIdx.x * 256 + threadIdx.x;
  int i = idx >> 10, o = idx & 1023;
  t[o * 1024 + i] = f2bf(w[idx]);
}

// memory-slot rows of K (keys 1024..1039 = sqrt(DK)*m_k ; 1040..1055 = 0)
__global__ void mk_fill_kernel(const float* __restrict__ m_k,
                               u16* __restrict__ kh, u16* __restrict__ kl) {
  int idx = blockIdx.x * 256 + threadIdx.x;     // B*H*32*128 = 262144
  int b = idx >> 15, h = (idx >> 12) & 7, ko = (idx >> 7) & 31, dk = idx & 127;
  float v = 0.f;
  if (ko < 16) v = 11.313708498984760f * m_k[ko * 1024 + h * 128 + dk];
  int dst = ((b * 8 + h) * KSP + 1024 + ko) * 128 + dk;
  u16 hh = f2bf(v);
  kh[dst] = hh;
  kl[dst] = f2bf(v - bf2f(hh));
}

// memory-slot keys of V^T (keys 1024..1039 = sqrt(M)*m_v ; 1040..1055 = 0)
__global__ void mv_fill_kernel(const float* __restrict__ m_v, u16* __restrict__ vt) {
  int idx = blockIdx.x * 256 + threadIdx.x;     // B*H*128*32 = 262144
  int b = idx >> 15, h = (idx >> 12) & 7, dv = (idx >> 5) & 127, ko = idx & 31;
  float v = (ko < 16) ? 4.0f * m_v[ko * 1024 + h * 128 + dv] : 0.f;
  vt[((b * 8 + h) * 128 + dv) * KSP + 1024 + ko] = f2bf(v);
}

// ---------------------------------------------------------------------- GEMM
// C(8192x1024) = A(8192x1024) @ B^T where B given as (1024 n-rows x 1024 k) rm.
// 128x128 tile, BK=64, 4 waves (2x2), 4x4 16x16x32 fragments per wave.
__device__ __forceinline__ void stage_tile(const u16* __restrict__ gbase,
                                           u16* sbase, int w, int lane) {
#pragma unroll
  for (int i = 0; i < 4; ++i) {
    const u16* src = gbase + (w * 32 + i * 8 + (lane >> 3)) * 1024 + (lane & 7) * 8;
    u16* dst = sbase + (w * 32 + i * 8) * 64;
    __builtin_amdgcn_global_load_lds(
        (const __attribute__((address_space(1))) void*)src,
        (__attribute__((address_space(3))) void*)dst, 16, 0, 0);
  }
}

enum { EPI_QSPLIT = 0, EPI_KSPLIT = 1, EPI_VT = 2, EPI_OUT = 3 };

template <bool SPLIT, int EPI>
__global__ __launch_bounds__(256)
void gemm_kernel(const u16* __restrict__ Ah, const u16* __restrict__ Al,
                 const u16* __restrict__ Bh, const u16* __restrict__ Bl,
                 const float* __restrict__ bias,
                 u16* __restrict__ oH, u16* __restrict__ oL,
                 float* __restrict__ oF) {
  __shared__ u16 sAh[128 * 64];
  __shared__ u16 sBh[128 * 64];
  __shared__ u16 sAl[128 * 64];
  __shared__ u16 sBl[128 * 64];
  const int lane = threadIdx.x & 63, w = threadIdx.x >> 6;
  const int bm = blockIdx.x & 63, bn = blockIdx.x >> 6;
  const int wr = w >> 1, wc = w & 1;

  f32x4 acc[4][4];
  const f32x4 fz = {0.f, 0.f, 0.f, 0.f};
#pragma unroll
  for (int m = 0; m < 4; ++m)
#pragma unroll
    for (int n = 0; n < 4; ++n) acc[m][n] = fz;

  for (int kt = 0; kt < 16; ++kt) {
    const int kb = kt * 64;
    stage_tile(Ah + bm * 128 * 1024 + kb, sAh, w, lane);
    stage_tile(Bh + bn * 128 * 1024 + kb, sBh, w, lane);
    if constexpr (SPLIT) {
      stage_tile(Al + bm * 128 * 1024 + kb, sAl, w, lane);
      stage_tile(Bl + bn * 128 * 1024 + kb, sBl, w, lane);
    }
    __syncthreads();
    const int ro = lane & 15;
#pragma unroll
    for (int kk = 0; kk < 2; ++kk) {
      const int co = kk * 32 + (lane >> 4) * 8;
      bf16x8 aH[4], bH[4], aL[4], bL[4];
#pragma unroll
      for (int m = 0; m < 4; ++m) {
        aH[m] = ld_bf8(&sAh[(wr * 64 + m * 16 + ro) * 64 + co]);
        if constexpr (SPLIT) aL[m] = ld_bf8(&sAl[(wr * 64 + m * 16 + ro) * 64 + co]);
      }
#pragma unroll
      for (int n = 0; n < 4; ++n) {
        bH[n] = ld_bf8(&sBh[(wc * 64 + n * 16 + ro) * 64 + co]);
        if constexpr (SPLIT) bL[n] = ld_bf8(&sBl[(wc * 64 + n * 16 + ro) * 64 + co]);
      }
#pragma unroll
      for (int m = 0; m < 4; ++m)
#pragma unroll
        for (int n = 0; n < 4; ++n) {
          acc[m][n] = MFMA_BF16(aH[m], bH[n], acc[m][n]);
          if constexpr (SPLIT) {
            acc[m][n] = MFMA_BF16(aH[m], bL[n], acc[m][n]);
            acc[m][n] = MFMA_BF16(aL[m], bH[n], acc[m][n]);
          }
        }
    }
    __syncthreads();
  }

  // epilogue
#pragma unroll
  for (int m = 0; m < 4; ++m)
#pragma unroll
    for (int n = 0; n < 4; ++n) {
      const int row0 = bm * 128 + wr * 64 + m * 16 + ((lane >> 4) << 2);
      const int col = bn * 128 + wc * 64 + n * 16 + (lane & 15);
      const float bv = bias[col];
#pragma unroll
      for (int r = 0; r < 4; ++r) {
        const float y = acc[m][n][r] + bv;
        const int row = row0 + r;
        if constexpr (EPI == EPI_QSPLIT) {
          u16 hh = f2bf(y);
          oH[row * 1024 + col] = hh;
          oL[row * 1024 + col] = f2bf(y - bf2f(hh));
        } else if constexpr (EPI == EPI_KSPLIT) {
          const int b = row >> 10, key = row & 1023;
          const int dst = ((b * 8 + (col >> 7)) * KSP + key) * 128 + (col & 127);
          u16 hh = f2bf(y);
          oH[dst] = hh;
          oL[dst] = f2bf(y - bf2f(hh));
        } else if constexpr (EPI == EPI_VT) {
          const int b = row >> 10, key = row & 1023;
          const int dst = ((b * 8 + (col >> 7)) * 128 + (col & 127)) * KSP + key;
          oH[dst] = f2bf(y);
        } else {
          oF[row * 1024 + col] = y;
        }
      }
    }
}

// ----------------------------------------------------------------- attention
// 4 waves / block, 16 q-rows per wave. 33 chunks of 32 keys (1056 padded).
// e = exp(scale*s) (no max subtraction; logits bounded), l = sum, O = eV / l.
__global__ __launch_bounds__(256)
void attn_kernel(const u16* __restrict__ qh, const u16* __restrict__ ql,
                 const u16* __restrict__ kh, const u16* __restrict__ kl,
                 const u16* __restrict__ vt, const int* __restrict__ mask,
                 float* __restrict__ att, u16* __restrict__ obuf,
                 float* __restrict__ inv_l) {
  __shared__ u16 plds[4][16][40];   // per-wave P transpose buffer (stride 40 -> 80B rows)
  const int lane = threadIdx.x & 63, w = threadIdx.x >> 6;
  const int blk = blockIdx.x;                 // 1024 blocks
  const int qblk = blk & 15;
  const int bh = blk >> 4;                    // b*8 + h
  const int h = bh & 7;
  const int b = bh >> 3;
  const int qrow0 = qblk * 64 + w * 16;       // within NQ
  const int grow0 = b * NQS + qrow0;          // row in (8192 x 1024) Q/O buffers
  const int ro = lane & 15, go = lane >> 4;

  // Q fragments (held for whole kernel)
  bf16x8 qhf[4], qlf[4];
#pragma unroll
  for (int kk = 0; kk < 4; ++kk) {
    const int off = (grow0 + ro) * 1024 + h * 128 + kk * 32 + go * 8;
    qhf[kk] = ld_bf8(&qh[off]);
    qlf[kk] = ld_bf8(&ql[off]);
  }

  const u16* khb = kh + (size_t)bh * KSP * 128;
  const u16* klb = kl + (size_t)bh * KSP * 128;
  const u16* vtb = vt + (size_t)bh * 128 * KSP;
  const int* maskb = mask + (size_t)bh * NQS * NKS;
  float* attb = att + (size_t)(bh * NQS + qrow0) * NKM;

  const f32x4 fz = {0.f, 0.f, 0.f, 0.f};
  f32x4 oacc[8];
#pragma unroll
  for (int n = 0; n < 8; ++n) oacc[n] = fz;
  float lsum[4] = {0.f, 0.f, 0.f, 0.f};

  for (int c = 0; c < 33; ++c) {
    const int kb = c * 32;
#pragma unroll
    for (int t = 0; t < 2; ++t) {
      const int key16 = kb + t * 16;
      f32x4 s = fz;
#pragma unroll
      for (int kk = 0; kk < 4; ++kk) {
        const int koff = (key16 + ro) * 128 + kk * 32 + go * 8;
        bf16x8 bhf = ld_bf8(&khb[koff]);
        bf16x8 blf = ld_bf8(&klb[koff]);
        s = MFMA_BF16(qhf[kk], bhf, s);
        s = MFMA_BF16(qhf[kk], blf, s);
        s = MFMA_BF16(qlf[kk], bhf, s);
      }
      const int key = key16 + ro;
#pragma unroll
      for (int r = 0; r < 4; ++r) {
        const int lrow = (go << 2) + r;
        const float sv = s[r] * SCALE_QK;
        bool dead;
        if (c < 32) {
          dead = (maskb[(qrow0 + lrow) * NKS + key] != 0);
        } else {
          dead = (key >= NKM);
        }
        const float e = dead ? 0.f : __expf(sv);
        lsum[r] += e;
        if (key < NKM) attb[(size_t)lrow * NKM + key] = e;   // unnormalized
        plds[w][lrow][t * 16 + ro] = f2bf(e);
      }
    }
    // PV: A = P(16x32) from LDS, B = V(32keys x 16dv) from vt
    bf16x8 pa = ld_bf8(&plds[w][ro][go * 8]);
#pragma unroll
    for (int n = 0; n < 8; ++n) {
      bf16x8 vb = ld_bf8(&vtb[(n * 16 + ro) * KSP + kb + go * 8]);
      oacc[n] = MFMA_BF16(pa, vb, oacc[n]);
    }
  }

  // row sums: reduce across the 16 lanes of each group
#pragma unroll
  for (int r = 0; r < 4; ++r) {
    lsum[r] += __shfl_xor(lsum[r], 1);
    lsum[r] += __shfl_xor(lsum[r], 2);
    lsum[r] += __shfl_xor(lsum[r], 4);
    lsum[r] += __shfl_xor(lsum[r], 8);
  }
  float inv[4];
#pragma unroll
  for (int r = 0; r < 4; ++r) inv[r] = 1.0f / lsum[r];
  if (ro == 0) {
#pragma unroll
    for (int r = 0; r < 4; ++r)
      inv_l[bh * NQS + qrow0 + (go << 2) + r] = inv[r];
  }
  // write O = oacc / l  (bf16, row = b*NQ+q, col = h*128+dv)
#pragma unroll
  for (int n = 0; n < 8; ++n)
#pragma unroll
    for (int r = 0; r < 4; ++r) {
      const float o = oacc[n][r] * inv[r];
      obuf[(grow0 + (go << 2) + r) * 1024 + h * 128 + n * 16 + ro] = f2bf(o);
    }
}

// att *= 1/l  (68157440 floats = 17039360 float4, 260 float4 per 1040-row)
__global__ void rescale_kernel(float* __restrict__ att, const float* __restrict__ inv_l) {
  const int total = 17039360;
  for (int i = blockIdx.x * blockDim.x + threadIdx.x; i < total;
       i += gridDim.x * blockDim.x) {
    const int row = i / 260;
    const float s = inv_l[row];
    float4 v = ((const float4*)att)[i];
    v.x *= s; v.y *= s; v.z *= s; v.w *= s;
    ((float4*)att)[i] = v;
  }
}

// --------------------------------------------------------------------- launch
extern "C" void kernel_launch(void* const* d_in, const int* in_sizes, int n_in,
                              void* d_out, int out_size, void* d_ws, size_t ws_size,
                              hipStream_t stream) {
  const float* queries = (const float*)d_in[0];
  const float* keys    = (const float*)d_in[1];
  const float* values  = (const float*)d_in[2];
  const int*   mask    = (const int*)d_in[3];
  const float* Wq = (const float*)d_in[4];
  const float* bq = (const float*)d_in[5];
  const float* Wk = (const float*)d_in[6];
  const float* bk = (const float*)d_in[7];
  const float* Wv = (const float*)d_in[8];
  const float* bv = (const float*)d_in[9];
  const float* Wo = (const float*)d_in[10];
  const float* bo = (const float*)d_in[11];
  const float* m_k = (const float*)d_in[12];
  const float* m_v = (const float*)d_in[13];

  if (ws_size < 164888576) return;   // workspace layout below needs ~157.3 MiB

  char* ws = (char*)d_ws;
  u16* xh_q = (u16*)(ws + 0);            // 16 MiB each
  u16* xl_q = (u16*)(ws + 16777216);
  u16* xh_k = (u16*)(ws + 33554432);
  u16* xl_k = (u16*)(ws + 50331648);
  u16* xv   = (u16*)(ws + 67108864);
  u16* wqth = (u16*)(ws + 83886080);     // 2 MiB each
  u16* wqtl = (u16*)(ws + 85983232);
  u16* wkth = (u16*)(ws + 88080384);
  u16* wktl = (u16*)(ws + 90177536);
  u16* wvt  = (u16*)(ws + 92274688);
  u16* wot  = (u16*)(ws + 94371840);
  u16* qh   = (u16*)(ws + 96468992);     // 16 MiB each
  u16* ql   = (u16*)(ws + 113246208);
  u16* kh   = (u16*)(ws + 130023424);    // 64*1056*128*2 = 16.5 MiB each
  u16* kl   = (u16*)(ws + 147324928);
  u16* vt   = (u16*)(ws + 33554432);     // alias xh_k/xl_k (dead after K-proj)
  u16* obuf = (u16*)(ws + 0);            // alias xh_q (dead after Q-proj)
  float* invl = (float*)(ws + 164626432);

  float* out = (float*)d_out;
  float* att = out + 8388608;

  // 1. input splits / converts
  split_kernel<<<2048, 256, 0, stream>>>(queries, xh_q, xl_q, 2097152);
  split_kernel<<<2048, 256, 0, stream>>>(keys, xh_k, xl_k, 2097152);
  cvt_kernel<<<2048, 256, 0, stream>>>(values, xv, 2097152);
  // 2. weight transposes
  wtrans_split_kernel<<<4096, 256, 0, stream>>>(Wq, wqth, wqtl);
  wtrans_split_kernel<<<4096, 256, 0, stream>>>(Wk, wkth, wktl);
  wtrans_cvt_kernel<<<4096, 256, 0, stream>>>(Wv, wvt);
  wtrans_cvt_kernel<<<4096, 256, 0, stream>>>(Wo, wot);
  // 3. projections
  gemm_kernel<true, EPI_QSPLIT><<<512, 256, 0, stream>>>(xh_q, xl_q, wqth, wqtl, bq, qh, ql, nullptr);
  gemm_kernel<true, EPI_KSPLIT><<<512, 256, 0, stream>>>(xh_k, xl_k, wkth, wktl, bk, kh, kl, nullptr);
  gemm_kernel<false, EPI_VT><<<512, 256, 0, stream>>>(xv, nullptr, wvt, nullptr, bv, vt, nullptr, nullptr);
  // 4. memory slots (K rows 1024..1055, V^T keys 1024..1055)
  mk_fill_kernel<<<1024, 256, 0, stream>>>(m_k, kh, kl);
  mv_fill_kernel<<<1024, 256, 0, stream>>>(m_v, vt);
  // 5. attention (unnormalized e to att, normalized O to obuf, 1/l to invl)
  attn_kernel<<<1024, 256, 0, stream>>>(qh, ql, kh, kl, vt, mask, att, obuf, invl);
  // 6. normalize att in place
  rescale_kernel<<<4096, 256, 0, stream>>>(att, invl);
  // 7. output projection
  gemm_kernel<false, EPI_OUT><<<512, 256, 0, stream>>>(obuf, nullptr, wot, nullptr, bo, nullptr, nullptr, out);
}

// Round 2
// 675.316 us; speedup vs baseline: 1.1286x; 1.1286x over previous
//
#include <hip/hip_runtime.h>

// ---------------------------------------------------------------------------
// AugmentedMemoryScaledDotProductAttention on MI355X (gfx950)
// B=8 H=8 NQ=NK=1024 D_MODEL=1024 DK=DV=128 M=16  (NKM=1040, padded to 1056)
//
// R2: attn latency fixes -- (a) mask pre-packed to bits via __ballot,
// (b) K/Kl/V^T chunk staged in LDS via async global_load_lds (XOR-swizzled K,
// padded V), shared by all 4 waves, single-buffer 2-barrier loop.
// ---------------------------------------------------------------------------

typedef unsigned short u16;
typedef unsigned int   u32;
typedef __bf16  bf16x8 __attribute__((ext_vector_type(8)));
typedef short   s16x8  __attribute__((ext_vector_type(8)));
typedef float   f32x4  __attribute__((ext_vector_type(4)));

#define MFMA_BF16(a, b, c) __builtin_amdgcn_mfma_f32_16x16x32_bf16((a), (b), (c), 0, 0, 0)

#define NB     8
#define NH     8
#define NQS    1024
#define NKS    1024
#define NKM    1040      // NK + M
#define KSP    1056      // padded key stride (NKM rounded to 32)
#define DKV    128
#define DMODEL 1024
#define SCALE_QK 0.088388347648318447f   // 1/sqrt(128)

__device__ __forceinline__ u16 f2bf(float f) {
  unsigned u = __builtin_bit_cast(unsigned, f);
  u += 0x7fffu + ((u >> 16) & 1u);
  return (u16)(u >> 16);
}
__device__ __forceinline__ float bf2f(u16 h) {
  unsigned u = ((unsigned)h) << 16;
  return __builtin_bit_cast(float, u);
}
__device__ __forceinline__ bf16x8 ld_bf8(const u16* p) {
  s16x8 r = *(const s16x8*)p;
  return __builtin_bit_cast(bf16x8, r);
}

// ---------------------------------------------------------------- elementwise
__global__ void split_kernel(const float* __restrict__ in,
                             u16* __restrict__ hi, u16* __restrict__ lo, int n4) {
  for (int i = blockIdx.x * blockDim.x + threadIdx.x; i < n4;
       i += gridDim.x * blockDim.x) {
    float4 v = ((const float4*)in)[i];
    ushort4 h, l;
    h.x = f2bf(v.x); l.x = f2bf(v.x - bf2f(h.x));
    h.y = f2bf(v.y); l.y = f2bf(v.y - bf2f(h.y));
    h.z = f2bf(v.z); l.z = f2bf(v.z - bf2f(h.z));
    h.w = f2bf(v.w); l.w = f2bf(v.w - bf2f(h.w));
    ((ushort4*)hi)[i] = h;
    ((ushort4*)lo)[i] = l;
  }
}

__global__ void cvt_kernel(const float* __restrict__ in, u16* __restrict__ out, int n4) {
  for (int i = blockIdx.x * blockDim.x + threadIdx.x; i < n4;
       i += gridDim.x * blockDim.x) {
    float4 v = ((const float4*)in)[i];
    ushort4 h;
    h.x = f2bf(v.x); h.y = f2bf(v.y); h.z = f2bf(v.z); h.w = f2bf(v.w);
    ((ushort4*)out)[i] = h;
  }
}

// W is (in=1024, out=1024) row-major; write Wt (out, in) row-major.
__global__ void wtrans_split_kernel(const float* __restrict__ w,
                                    u16* __restrict__ th, u16* __restrict__ tl) {
  int idx = blockIdx.x * 256 + threadIdx.x;   // 1M threads
  int i = idx >> 10, o = idx & 1023;
  float v = w[idx];
  u16 hh = f2bf(v);
  th[o * 1024 + i] = hh;
  tl[o * 1024 + i] = f2bf(v - bf2f(hh));
}

__global__ void wtrans_cvt_kernel(const float* __restrict__ w, u16* __restrict__ t) {
  int idx = blockIdx.x * 256 + threadIdx.x;
  int i = idx >> 10, o = idx & 1023;
  t[o * 1024 + i] = f2bf(w[idx]);
}

// memory-slot rows of K (keys 1024..1039 = sqrt(DK)*m_k ; 1040..1055 = 0)
__global__ void mk_fill_kernel(const float* __restrict__ m_k,
                               u16* __restrict__ kh, u16* __restrict__ kl) {
  int idx = blockIdx.x * 256 + threadIdx.x;     // B*H*32*128 = 262144
  int b = idx >> 15, h = (idx >> 12) & 7, ko = (idx >> 7) & 31, dk = idx & 127;
  float v = 0.f;
  if (ko < 16) v = 11.313708498984760f * m_k[ko * 1024 + h * 128 + dk];
  int dst = ((b * 8 + h) * KSP + 1024 + ko) * 128 + dk;
  u16 hh = f2bf(v);
  kh[dst] = hh;
  kl[dst] = f2bf(v - bf2f(hh));
}

// memory-slot keys of V^T (keys 1024..1039 = sqrt(M)*m_v ; 1040..1055 = 0)
__global__ void mv_fill_kernel(const float* __restrict__ m_v, u16* __restrict__ vt) {
  int idx = blockIdx.x * 256 + threadIdx.x;     // B*H*128*32 = 262144
  int b = idx >> 15, h = (idx >> 12) & 7, dv = (idx >> 5) & 127, ko = idx & 31;
  float v = (ko < 16) ? 4.0f * m_v[ko * 1024 + h * 128 + dv] : 0.f;
  vt[((b * 8 + h) * 128 + dv) * KSP + 1024 + ko] = f2bf(v);
}

// mask (int32, !=0 means masked/dead) -> bit words. mbits[(bh*1024+q)*33 + w]
__global__ void maskbits_kernel(const int* __restrict__ mask, u32* __restrict__ mbits) {
  const int lane = threadIdx.x & 63;
  const int nwave = (gridDim.x * blockDim.x) >> 6;
  int wid = (blockIdx.x * blockDim.x + threadIdx.x) >> 6;
  for (int i = wid; i < 1048576; i += nwave) {        // 2^20 groups of 64 keys
    int m = mask[i * 64 + lane];
    unsigned long long bal = __ballot(m != 0);
    int row = i >> 4;                                  // (bh*1024+q)
    int col = (i * 2) & 31;
    if (lane == 0) mbits[row * 33 + col] = (u32)bal;
    else if (lane == 32) mbits[row * 33 + col + 1] = (u32)(bal >> 32);
  }
}

// word 32 of each row: keys 1024..1039 alive, 1040..1055 dead
__global__ void maskfill_kernel(u32* __restrict__ mbits) {
  int idx = blockIdx.x * 256 + threadIdx.x;   // 65536
  mbits[idx * 33 + 32] = 0xFFFF0000u;
}

// ---------------------------------------------------------------------- GEMM
// C(8192x1024) = A(8192x1024) @ B^T where B given as (1024 n-rows x 1024 k) rm.
// 128x128 tile, BK=64, 4 waves (2x2), 4x4 16x16x32 fragments per wave.
__device__ __forceinline__ void stage_tile(const u16* __restrict__ gbase,
                                           u16* sbase, int w, int lane) {
#pragma unroll
  for (int i = 0; i < 4; ++i) {
    const u16* src = gbase + (w * 32 + i * 8 + (lane >> 3)) * 1024 + (lane & 7) * 8;
    u16* dst = sbase + (w * 32 + i * 8) * 64;
    __builtin_amdgcn_global_load_lds(
        (const __attribute__((address_space(1))) void*)src,
        (__attribute__((address_space(3))) void*)dst, 16, 0, 0);
  }
}

enum { EPI_QSPLIT = 0, EPI_KSPLIT = 1, EPI_VT = 2, EPI_OUT = 3 };

template <bool SPLIT, int EPI>
__global__ __launch_bounds__(256)
void gemm_kernel(const u16* __restrict__ Ah, const u16* __restrict__ Al,
                 const u16* __restrict__ Bh, const u16* __restrict__ Bl,
                 const float* __restrict__ bias,
                 u16* __restrict__ oH, u16* __restrict__ oL,
                 float* __restrict__ oF) {
  __shared__ u16 sAh[128 * 64];
  __shared__ u16 sBh[128 * 64];
  __shared__ u16 sAl[128 * 64];
  __shared__ u16 sBl[128 * 64];
  const int lane = threadIdx.x & 63, w = threadIdx.x >> 6;
  const int bm = blockIdx.x & 63, bn = blockIdx.x >> 6;
  const int wr = w >> 1, wc = w & 1;

  f32x4 acc[4][4];
  const f32x4 fz = {0.f, 0.f, 0.f, 0.f};
#pragma unroll
  for (int m = 0; m < 4; ++m)
#pragma unroll
    for (int n = 0; n < 4; ++n) acc[m][n] = fz;

  for (int kt = 0; kt < 16; ++kt) {
    const int kb = kt * 64;
    stage_tile(Ah + bm * 128 * 1024 + kb, sAh, w, lane);
    stage_tile(Bh + bn * 128 * 1024 + kb, sBh, w, lane);
    if constexpr (SPLIT) {
      stage_tile(Al + bm * 128 * 1024 + kb, sAl, w, lane);
      stage_tile(Bl + bn * 128 * 1024 + kb, sBl, w, lane);
    }
    __syncthreads();
    const int ro = lane & 15;
#pragma unroll
    for (int kk = 0; kk < 2; ++kk) {
      const int co = kk * 32 + (lane >> 4) * 8;
      bf16x8 aH[4], bH[4], aL[4], bL[4];
#pragma unroll
      for (int m = 0; m < 4; ++m) {
        aH[m] = ld_bf8(&sAh[(wr * 64 + m * 16 + ro) * 64 + co]);
        if constexpr (SPLIT) aL[m] = ld_bf8(&sAl[(wr * 64 + m * 16 + ro) * 64 + co]);
      }
#pragma unroll
      for (int n = 0; n < 4; ++n) {
        bH[n] = ld_bf8(&sBh[(wc * 64 + n * 16 + ro) * 64 + co]);
        if constexpr (SPLIT) bL[n] = ld_bf8(&sBl[(wc * 64 + n * 16 + ro) * 64 + co]);
      }
#pragma unroll
      for (int m = 0; m < 4; ++m)
#pragma unroll
        for (int n = 0; n < 4; ++n) {
          acc[m][n] = MFMA_BF16(aH[m], bH[n], acc[m][n]);
          if constexpr (SPLIT) {
            acc[m][n] = MFMA_BF16(aH[m], bL[n], acc[m][n]);
            acc[m][n] = MFMA_BF16(aL[m], bH[n], acc[m][n]);
          }
        }
    }
    __syncthreads();
  }

  // epilogue
#pragma unroll
  for (int m = 0; m < 4; ++m)
#pragma unroll
    for (int n = 0; n < 4; ++n) {
      const int row0 = bm * 128 + wr * 64 + m * 16 + ((lane >> 4) << 2);
      const int col = bn * 128 + wc * 64 + n * 16 + (lane & 15);
      const float bv = bias[col];
#pragma unroll
      for (int r = 0; r < 4; ++r) {
        const float y = acc[m][n][r] + bv;
        const int row = row0 + r;
        if constexpr (EPI == EPI_QSPLIT) {
          u16 hh = f2bf(y);
          oH[row * 1024 + col] = hh;
          oL[row * 1024 + col] = f2bf(y - bf2f(hh));
        } else if constexpr (EPI == EPI_KSPLIT) {
          const int b = row >> 10, key = row & 1023;
          const int dst = ((b * 8 + (col >> 7)) * KSP + key) * 128 + (col & 127);
          u16 hh = f2bf(y);
          oH[dst] = hh;
          oL[dst] = f2bf(y - bf2f(hh));
        } else if constexpr (EPI == EPI_VT) {
          const int b = row >> 10, key = row & 1023;
          const int dst = ((b * 8 + (col >> 7)) * 128 + (col & 127)) * KSP + key;
          oH[dst] = f2bf(y);
        } else {
          oF[row * 1024 + col] = y;
        }
      }
    }
}

// ----------------------------------------------------------------- attention
// 4 waves / block, 16 q-rows per wave, 64 q-rows per block. 33 chunks of 32
// keys. Per chunk: async-stage K-hi/K-lo (XOR-swizzled) + V^T (padded) into
// LDS shared by all waves; QK^T(split) -> e=exp -> att store + P to plds; PV.
__device__ __forceinline__ void stage_chunkK(const u16* __restrict__ g,
                                             u16* s, int tid) {
#pragma unroll
  for (int p = 0; p < 2; ++p) {
    const int d = p * 4096 + tid * 16;       // LDS byte offset (linear)
    const int r = d >> 8;                    // key row 0..31
    const int wb = d & 255;                  // 16B-aligned col byte
    const u16* src = g + r * 128 + (((wb ^ ((r & 7) << 4))) >> 1);
    __builtin_amdgcn_global_load_lds(
        (const __attribute__((address_space(1))) void*)src,
        (__attribute__((address_space(3))) void*)((char*)s + d), 16, 0, 0);
  }
}

// V^T tile: 128 dv-rows x 40 cols (80B rows, cols 32..39 pad). 640 16B chunks.
__device__ __forceinline__ void stage_chunkV(const u16* __restrict__ g,
                                             u16* s, int tid) {
#pragma unroll
  for (int p = 0; p < 3; ++p) {
    const int t = p * 256 + tid;
    if (t < 640) {
      const int r = t / 5;
      const int wb = (t - r * 5) * 16;       // 0,16,32,48,64
      const u16* src = (wb == 64) ? (g + r * KSP)           // pad: safe dummy
                                  : (g + r * KSP + (wb >> 1));
      __builtin_amdgcn_global_load_lds(
          (const __attribute__((address_space(1))) void*)src,
          (__attribute__((address_space(3))) void*)((char*)s + t * 16), 16, 0, 0);
    }
  }
}

__global__ __launch_bounds__(256)
void attn_kernel(const u16* __restrict__ qh, const u16* __restrict__ ql,
                 const u16* __restrict__ kh, const u16* __restrict__ kl,
                 const u16* __restrict__ vt, const u32* __restrict__ mbits,
                 float* __restrict__ att, u16* __restrict__ obuf,
                 float* __restrict__ inv_l) {
  __shared__ u16 sKh[32 * 128];
  __shared__ u16 sKl[32 * 128];
  __shared__ u16 sVt[128 * 40];
  __shared__ u16 plds[4][16][40];
  const int tid = threadIdx.x;
  const int lane = tid & 63, w = tid >> 6;
  const int blk = blockIdx.x;                 // 1024 blocks
  const int qblk = blk & 15;
  const int bh = blk >> 4;                    // b*8 + h
  const int h = bh & 7;
  const int b = bh >> 3;
  const int qrow0 = qblk * 64 + w * 16;       // within NQ
  const int grow0 = b * NQS + qrow0;          // row in (8192 x 1024) Q/O buffers
  const int ro = lane & 15, go = lane >> 4;

  // Q fragments (held for whole kernel)
  bf16x8 qhf[4], qlf[4];
#pragma unroll
  for (int kk = 0; kk < 4; ++kk) {
    const int off = (grow0 + ro) * 1024 + h * 128 + kk * 32 + go * 8;
    qhf[kk] = ld_bf8(&qh[off]);
    qlf[kk] = ld_bf8(&ql[off]);
  }

  const u16* khb = kh + (size_t)bh * KSP * 128;
  const u16* klb = kl + (size_t)bh * KSP * 128;
  const u16* vtb = vt + (size_t)bh * 128 * KSP;
  const u32* mbb = mbits + (size_t)bh * NQS * 33;
  float* attb = att + (size_t)(bh * NQS + qrow0) * NKM;

  const f32x4 fz = {0.f, 0.f, 0.f, 0.f};
  f32x4 oacc[8];
#pragma unroll
  for (int n = 0; n < 8; ++n) oacc[n] = fz;
  float lsum[4] = {0.f, 0.f, 0.f, 0.f};

  for (int c = 0; c < 33; ++c) {
    const int kb = c * 32;
    stage_chunkK(khb + kb * 128, sKh, tid);
    stage_chunkK(klb + kb * 128, sKl, tid);
    stage_chunkV(vtb + kb, sVt, tid);
    __syncthreads();

    u32 mw[4];
#pragma unroll
    for (int r = 0; r < 4; ++r) mw[r] = mbb[(qrow0 + (go << 2) + r) * 33 + c];

#pragma unroll
    for (int t = 0; t < 2; ++t) {
      f32x4 s = fz;
      const int rr = t * 16 + ro;                  // key row in chunk
      const int sw = (rr & 7) << 4;
#pragma unroll
      for (int kk = 0; kk < 4; ++kk) {
        const int off = rr * 256 + ((kk * 64 + go * 16) ^ sw);
        bf16x8 bhf = ld_bf8((const u16*)((const char*)sKh + off));
        bf16x8 blf = ld_bf8((const u16*)((const char*)sKl + off));
        s = MFMA_BF16(qhf[kk], bhf, s);
        s = MFMA_BF16(qhf[kk], blf, s);
        s = MFMA_BF16(qlf[kk], bhf, s);
      }
      const int key_in = t * 16 + ro;
#pragma unroll
      for (int r = 0; r < 4; ++r) {
        const int lrow = (go << 2) + r;
        const float sv = s[r] * SCALE_QK;
        const bool dead = (mw[r] >> key_in) & 1;
        const float e = dead ? 0.f : __expf(sv);
        lsum[r] += e;
        if (kb + key_in < NKM) attb[(size_t)lrow * NKM + kb + key_in] = e;
        plds[w][lrow][t * 16 + ro] = f2bf(e);
      }
    }
    // PV: A = P(16x32) from plds, B = V^T(dv x key) tile from sVt
    bf16x8 pa = ld_bf8(&plds[w][ro][go * 8]);
#pragma unroll
    for (int n = 0; n < 8; ++n) {
      bf16x8 vb = ld_bf8((const u16*)((const char*)sVt + (n * 16 + ro) * 80 + go * 16));
      oacc[n] = MFMA_BF16(pa, vb, oacc[n]);
    }
    __syncthreads();
  }

  // row sums: reduce across the 16 lanes of each group
#pragma unroll
  for (int r = 0; r < 4; ++r) {
    lsum[r] += __shfl_xor(lsum[r], 1);
    lsum[r] += __shfl_xor(lsum[r], 2);
    lsum[r] += __shfl_xor(lsum[r], 4);
    lsum[r] += __shfl_xor(lsum[r], 8);
  }
  float inv[4];
#pragma unroll
  for (int r = 0; r < 4; ++r) inv[r] = 1.0f / lsum[r];
  if (ro == 0) {
#pragma unroll
    for (int r = 0; r < 4; ++r)
      inv_l[bh * NQS + qrow0 + (go << 2) + r] = inv[r];
  }
  // write O = oacc / l  (bf16, row = b*NQ+q, col = h*128+dv)
#pragma unroll
  for (int n = 0; n < 8; ++n)
#pragma unroll
    for (int r = 0; r < 4; ++r) {
      const float o = oacc[n][r] * inv[r];
      obuf[(grow0 + (go << 2) + r) * 1024 + h * 128 + n * 16 + ro] = f2bf(o);
    }
}

// att *= 1/l  (68157440 floats = 17039360 float4, 260 float4 per 1040-row)
__global__ void rescale_kernel(float* __restrict__ att, const float* __restrict__ inv_l) {
  const int total = 17039360;
  for (int i = blockIdx.x * blockDim.x + threadIdx.x; i < total;
       i += gridDim.x * blockDim.x) {
    const int row = i / 260;
    const float s = inv_l[row];
    float4 v = ((const float4*)att)[i];
    v.x *= s; v.y *= s; v.z *= s; v.w *= s;
    ((float4*)att)[i] = v;
  }
}

// --------------------------------------------------------------------- launch
extern "C" void kernel_launch(void* const* d_in, const int* in_sizes, int n_in,
                              void* d_out, int out_size, void* d_ws, size_t ws_size,
                              hipStream_t stream) {
  const float* queries = (const float*)d_in[0];
  const float* keys    = (const float*)d_in[1];
  const float* values  = (const float*)d_in[2];
  const int*   mask    = (const int*)d_in[3];
  const float* Wq = (const float*)d_in[4];
  const float* bq = (const float*)d_in[5];
  const float* Wk = (const float*)d_in[6];
  const float* bk = (const float*)d_in[7];
  const float* Wv = (const float*)d_in[8];
  const float* bv = (const float*)d_in[9];
  const float* Wo = (const float*)d_in[10];
  const float* bo = (const float*)d_in[11];
  const float* m_k = (const float*)d_in[12];
  const float* m_v = (const float*)d_in[13];

  if (ws_size < 164888576) return;   // workspace layout below needs ~157.3 MiB

  char* ws = (char*)d_ws;
  u16* xh_q = (u16*)(ws + 0);            // 16 MiB each
  u16* xl_q = (u16*)(ws + 16777216);
  u16* xh_k = (u16*)(ws + 33554432);
  u16* xl_k = (u16*)(ws + 50331648);
  u16* xv   = (u16*)(ws + 67108864);
  u16* wqth = (u16*)(ws + 83886080);     // 2 MiB each
  u16* wqtl = (u16*)(ws + 85983232);
  u16* wkth = (u16*)(ws + 88080384);
  u16* wktl = (u16*)(ws + 90177536);
  u16* wvt  = (u16*)(ws + 92274688);
  u16* wot  = (u16*)(ws + 94371840);
  u16* qh   = (u16*)(ws + 96468992);     // 16 MiB each
  u16* ql   = (u16*)(ws + 113246208);
  u16* kh   = (u16*)(ws + 130023424);    // 64*1056*128*2 = 16.5 MiB each
  u16* kl   = (u16*)(ws + 147324928);
  u16* vt   = (u16*)(ws + 33554432);     // alias xh_k/xl_k (dead after K-proj)
  u16* obuf = (u16*)(ws + 0);            // alias xh_q (dead after Q-proj)
  u32* mbits = (u32*)(ws + 67108864);    // alias xv (dead after V-proj), 8.65 MiB
  float* invl = (float*)(ws + 164626432);

  float* out = (float*)d_out;
  float* att = out + 8388608;

  // 1. input splits / converts
  split_kernel<<<2048, 256, 0, stream>>>(queries, xh_q, xl_q, 2097152);
  split_kernel<<<2048, 256, 0, stream>>>(keys, xh_k, xl_k, 2097152);
  cvt_kernel<<<2048, 256, 0, stream>>>(values, xv, 2097152);
  // 2. weight transposes
  wtrans_split_kernel<<<4096, 256, 0, stream>>>(Wq, wqth, wqtl);
  wtrans_split_kernel<<<4096, 256, 0, stream>>>(Wk, wkth, wktl);
  wtrans_cvt_kernel<<<4096, 256, 0, stream>>>(Wv, wvt);
  wtrans_cvt_kernel<<<4096, 256, 0, stream>>>(Wo, wot);
  // 3. projections
  gemm_kernel<true, EPI_QSPLIT><<<512, 256, 0, stream>>>(xh_q, xl_q, wqth, wqtl, bq, qh, ql, nullptr);
  gemm_kernel<true, EPI_KSPLIT><<<512, 256, 0, stream>>>(xh_k, xl_k, wkth, wktl, bk, kh, kl, nullptr);
  gemm_kernel<false, EPI_VT><<<512, 256, 0, stream>>>(xv, nullptr, wvt, nullptr, bv, vt, nullptr, nullptr);
  // 4. mask bit-pack (mbits aliases xv -- must run after V-proj)
  maskbits_kernel<<<2048, 256, 0, stream>>>(mask, mbits);
  maskfill_kernel<<<256, 256, 0, stream>>>(mbits);
  // 5. memory slots (K rows 1024..1055, V^T keys 1024..1055)
  mk_fill_kernel<<<1024, 256, 0, stream>>>(m_k, kh, kl);
  mv_fill_kernel<<<1024, 256, 0, stream>>>(m_v, vt);
  // 6. attention (unnormalized e to att, normalized O to obuf, 1/l to invl)
  attn_kernel<<<1024, 256, 0, stream>>>(qh, ql, kh, kl, vt, mbits, att, obuf, invl);
  // 7. normalize att in place
  rescale_kernel<<<4096, 256, 0, stream>>>(att, invl);
  // 8. output projection
  gemm_kernel<false, EPI_OUT><<<512, 256, 0, stream>>>(obuf, nullptr, wot, nullptr, bo, nullptr, nullptr, out);
}